// Round 5
// baseline (210.108 us; speedup 1.0000x reference)
//
#include <hip/hip_runtime.h>
#include <hip/hip_fp16.h>
#include <math.h>

#define N 20000
#define F 128
#define C1 256   // HEADS*HIDDEN
#define HEADS 8
#define HID 32
#define NC 40
#define NCP 64   // padded h2h row stride (1 cache line)
#define NEG 0.2f

#define BSHIFT 7
#define NB 157        // buckets of 128 nodes
#define HBLOCKS 256
#define HM (NB * HBLOCKS)

#define PREPW_BLOCKS 16
#define W2PW_BLOCKS 6   // 24 frags * 64 lanes = 1536 half8 slots

#define QS ((size_t)N * 64)   // quarter-plane element stride

typedef _Float16 half8 __attribute__((ext_vector_type(8)));
typedef float f32x4 __attribute__((ext_vector_type(4)));

__device__ __forceinline__ int edge_stride(const int* ei) {
    return (ei[1] == 0 && ei[3] == 0 && ei[5] == 0 && ei[7] == 0 && ei[9] == 0) ? 2 : 1;
}

__device__ __forceinline__ float lrelu(float v) { return v > 0.f ? v : NEG * v; }

// ---- K0: fused prep (W1 swizzle + W2 swizzle) + bucket histogram (LDS atomics only)
__global__ __launch_bounds__(256) void k_misc(
    const float* __restrict__ W1, _Float16* __restrict__ w1sw,
    const float* __restrict__ W2, _Float16* __restrict__ w2sw,
    const int* __restrict__ ei, int E, int* __restrict__ hist)
{
    const int b = blockIdx.x;
    const int tid = threadIdx.x;
    if (b < PREPW_BLOCKS) {
        const int slot = b * 256 + tid;
        const int lane = slot & 63;
        const int tile = slot >> 6;
        const int nt = tile & 15, ks = tile >> 4;
        const int n = nt * 16 + (lane & 15);
        const int k0 = ks * 32 + (lane >> 4) * 8;
        half8 tmp;
#pragma unroll
        for (int j = 0; j < 8; j++) tmp[j] = (_Float16)W1[(k0 + j) * C1 + n];
        *reinterpret_cast<half8*>(&w1sw[(size_t)slot * 8]) = tmp;
    } else if (b < PREPW_BLOCKS + W2PW_BLOCKS) {
        const int slot = (b - PREPW_BLOCKS) * 256 + tid;   // 0..1535
        const int lane = slot & 63;
        const int f = slot >> 6;          // 0..23
        const int nt = f % 3, ks = f / 3;
        const int n = nt * 16 + (lane & 15);
        const int k0 = ks * 32 + (lane >> 4) * 8;
        half8 tmp;
#pragma unroll
        for (int j = 0; j < 8; j++)
            tmp[j] = (n < NC) ? (_Float16)W2[(k0 + j) * NC + n] : (_Float16)0.f;
        *reinterpret_cast<half8*>(&w2sw[(size_t)slot * 8]) = tmp;
    } else {
        __shared__ int hcnt[NB];
        const int hb = b - PREPW_BLOCKS - W2PW_BLOCKS;
        if (tid < NB) hcnt[tid] = 0;
        __syncthreads();
        const int ET = E + N;
        const int per = (ET + HBLOCKS - 1) / HBLOCKS;
        const int lo = hb * per;
        const int hi = (lo + per < ET) ? (lo + per) : ET;
        const int st = edge_stride(ei);
        for (int i = lo + tid; i < hi; i += 256) {
            const int d = (i < E) ? ei[(size_t)st * (E + i)] : (i - E);
            atomicAdd(&hcnt[d >> BSHIFT], 1);
        }
        __syncthreads();
        if (tid < NB) hist[tid * HBLOCKS + hb] = hcnt[tid];
    }
}

// ---- K1: h1 = x @ W1 via MFMA; h1 written as FOUR 64-ch quarter planes
//      (each 2.56 MB -> L2-resident per XCD with blockIdx&3 steering in k_agg1).
__global__ __launch_bounds__(256) void k_gemm1_mfma(
    const float* __restrict__ x, const _Float16* __restrict__ w1sw,
    const float* __restrict__ a1s, const float* __restrict__ a1d,
    __half* __restrict__ qh1,
    float* __restrict__ as1, float* __restrict__ ad1)
{
    const int lane = threadIdx.x & 63;
    const int wid = (blockIdx.x * 256 + threadIdx.x) >> 6;
    const int m0 = wid * 16;
    const int g = lane >> 4, lm = lane & 15;
    const int arow = m0 + lm;
    half8 a[4];
    if (arow < N) {
        const float* xr = x + (size_t)arow * F;
#pragma unroll
        for (int ks = 0; ks < 4; ks++) {
            const float4 v0 = *reinterpret_cast<const float4*>(&xr[ks * 32 + g * 8]);
            const float4 v1 = *reinterpret_cast<const float4*>(&xr[ks * 32 + g * 8 + 4]);
            half8 t;
            t[0] = (_Float16)v0.x; t[1] = (_Float16)v0.y; t[2] = (_Float16)v0.z; t[3] = (_Float16)v0.w;
            t[4] = (_Float16)v1.x; t[5] = (_Float16)v1.y; t[6] = (_Float16)v1.z; t[7] = (_Float16)v1.w;
            a[ks] = t;
        }
    } else {
#pragma unroll
        for (int ks = 0; ks < 4; ks++) {
            half8 t;
#pragma unroll
            for (int j = 0; j < 8; j++) t[j] = (_Float16)0.f;
            a[ks] = t;
        }
    }
    const int rbase = m0 + g * 4;
    float ps[4] = {0.f, 0.f, 0.f, 0.f}, pd[4] = {0.f, 0.f, 0.f, 0.f};
#pragma unroll
    for (int nt = 0; nt < 16; nt++) {
        f32x4 acc = {0.f, 0.f, 0.f, 0.f};
#pragma unroll
        for (int ks = 0; ks < 4; ks++) {
            const half8 bfr = *reinterpret_cast<const half8*>(&w1sw[(size_t)((ks * 16 + nt) * 64 + lane) * 8]);
            acc = __builtin_amdgcn_mfma_f32_16x16x32_f16(a[ks], bfr, acc, 0, 0, 0);
        }
        const int col = nt * 16 + lm;
        const int q = col >> 6, cq = col & 63;
        const float av = a1s[col], dv = a1d[col];
#pragma unroll
        for (int r = 0; r < 4; r++) {
            const int row = rbase + r;
            if (row < N) qh1[(size_t)q * QS + (size_t)row * 64 + cq] = __float2half((float)acc[r]);
            ps[r] = fmaf((float)acc[r], av, ps[r]);
            pd[r] = fmaf((float)acc[r], dv, pd[r]);
        }
        if (nt & 1) {
#pragma unroll
            for (int off = 1; off <= 8; off <<= 1) {
#pragma unroll
                for (int r = 0; r < 4; r++) {
                    ps[r] += __shfl_xor(ps[r], off);
                    pd[r] += __shfl_xor(pd[r], off);
                }
            }
            if (lm == 0) {
                const int head = nt >> 1;
#pragma unroll
                for (int r = 0; r < 4; r++) {
                    const int row = rbase + r;
                    if (row < N) {
                        as1[row * HEADS + head] = ps[r];
                        ad1[row * HEADS + head] = pd[r];
                    }
                }
            }
#pragma unroll
            for (int r = 0; r < 4; r++) { ps[r] = 0.f; pd[r] = 0.f; }
        }
    }
}

// ---- K2: merged bucket-sum + global scan + per-bucket row scan (one kernel).
__global__ __launch_bounds__(256) void k_hscan2(int* __restrict__ hist)
{
    __shared__ int bs[160];
    __shared__ int wbase[4];
    __shared__ int base_s;
    const int b = blockIdx.x;
    const int tid = threadIdx.x;
    const int lane = tid & 63, wid = tid >> 6;
    if (tid < NB) {
        const int4* hp = (const int4*)&hist[tid * HBLOCKS];
        int s = 0;
#pragma unroll 4
        for (int k = 0; k < 64; k++) { const int4 v = hp[k]; s += (v.x + v.y) + (v.z + v.w); }
        bs[tid] = s;
    }
    __syncthreads();
    {
        const int vin = (tid < NB) ? bs[tid] : 0;
        int v = vin;
#pragma unroll
        for (int off = 1; off < 64; off <<= 1) {
            const int u = __shfl_up(v, off, 64);
            if (lane >= off) v += u;
        }
        if (lane == 63) wbase[wid] = v;
        __syncthreads();
        if (tid < 64) {
            int w = (lane < 4) ? wbase[lane] : 0;
            const int orig = w;
#pragma unroll
            for (int off = 1; off < 4; off <<= 1) {
                const int u = __shfl_up(w, off, 64);
                if (lane >= off) w += u;
            }
            if (lane < 4) wbase[lane] = w - orig;
        }
        __syncthreads();
        if (tid == b) base_s = wbase[wid] + v - vin;
    }
    __syncthreads();
    const int vin2 = hist[b * HBLOCKS + tid];
    int v2 = vin2;
#pragma unroll
    for (int off = 1; off < 64; off <<= 1) {
        const int u = __shfl_up(v2, off, 64);
        if (lane >= off) v2 += u;
    }
    if (lane == 63) wbase[wid] = v2;
    __syncthreads();
    if (tid < 64) {
        int w = (lane < 4) ? wbase[lane] : 0;
        const int orig = w;
#pragma unroll
        for (int off = 1; off < 4; off <<= 1) {
            const int u = __shfl_up(w, off, 64);
            if (lane >= off) w += u;
        }
        if (lane < 4) wbase[lane] = w - orig;
    }
    __syncthreads();
    hist[b * HBLOCKS + tid] = base_s + wbase[wid] + v2 - vin2;
}

// ---- K3: scatter edges into coarse buckets. LDS cursors only.
__global__ __launch_bounds__(256) void k_scatter(
    const int* __restrict__ ei, int E, const int* __restrict__ hist,
    int* __restrict__ buck)
{
    __shared__ int cur[NB];
    const int hb = blockIdx.x;
    const int tid = threadIdx.x;
    if (tid < NB) cur[tid] = hist[tid * HBLOCKS + hb];
    __syncthreads();
    const int ET = E + N;
    const int per = (ET + HBLOCKS - 1) / HBLOCKS;
    const int lo = hb * per;
    const int hi = (lo + per < ET) ? (lo + per) : ET;
    const int st = edge_stride(ei);
    for (int i = lo + tid; i < hi; i += 256) {
        int s, d;
        if (i < E) { s = ei[(size_t)st * i]; d = ei[(size_t)st * (E + i)]; }
        else       { s = i - E; d = i - E; }
        const int slot = atomicAdd(&cur[d >> BSHIFT], 1);
        buck[slot] = ((d & 127) << 16) | s;
    }
}

// ---- K4: per-bucket counting sort -> csr + rowptr (+ zero sentinels past ET).
__global__ __launch_bounds__(256) void k_bucket(
    const int* __restrict__ hist, const int* __restrict__ buck, int ET,
    int* __restrict__ csr, int* __restrict__ rowptr)
{
    __shared__ int cnt[128];
    __shared__ int pfx[128];
    const int b = blockIdx.x;
    const int tid = threadIdx.x;
    const int start = hist[b * HBLOCKS];
    const int end = (b == NB - 1) ? ET : hist[(b + 1) * HBLOCKS];
    if (tid < 128) cnt[tid] = 0;
    __syncthreads();
    for (int i = start + tid; i < end; i += 256)
        atomicAdd(&cnt[buck[i] >> 16], 1);
    __syncthreads();
    if (tid < 128) pfx[tid] = cnt[tid];
    __syncthreads();
    for (int off = 1; off < 128; off <<= 1) {
        int u = 0;
        if (tid < 128 && tid >= off) u = pfx[tid - off];
        __syncthreads();
        if (tid < 128) pfx[tid] += u;
        __syncthreads();
    }
    if (tid < 128) {
        const int node = b * 128 + tid;
        const int ebase = start + pfx[tid] - cnt[tid];
        if (node < N) rowptr[node] = ebase;
        cnt[tid] = ebase;
    }
    if (b == NB - 1 && tid == 0) rowptr[N] = ET;
    if (b == NB - 1 && tid < 32) csr[ET + tid] = 0;   // sentinels: safe tail/producer reads
    __syncthreads();
    for (int i = start + tid; i < end; i += 256) {
        const int val = buck[i];
        const int slot = atomicAdd(&cnt[val >> 16], 1);
        csr[slot] = val & 0xFFFF;
    }
}

// ---- K6: layer-1 aggregation, one WAVE per (node, quarter=64ch). Quarter plane
//      is 2.56MB -> L2-RESIDENT per XCD (hq = blockIdx&3 ~ XCD parity steering).
//      Weights: per 32-edge burst, lane l produces w for (edge l>>1, head hq*2+(l&1))
//      -> exactly 1 exp per lane per burst; consumers fetch via one __shfl/edge.
//      Producer inputs for the NEXT burst are prefetched -> exp chain off critical path.
__global__ __launch_bounds__(256) void k_agg1(
    const int* __restrict__ rowptr, const int* __restrict__ csr,
    const __half* __restrict__ qh1,
    const float* __restrict__ as1, const float* __restrict__ ad1,
    const float* __restrict__ b1, __half* __restrict__ h1p)
{
    const int tid = threadIdx.x;
    const int lane = tid & 63;
    const int wv = tid >> 6;
    const int hq = blockIdx.x & 3;               // quarter -> XCD steering
    const int n = (blockIdx.x >> 2) * 4 + wv;    // node
    const int ch = hq * 64 + lane;               // global channel owned by this lane
    // producer role
    const int jp = lane >> 1;                    // edge slot 0..31
    const int hp = hq * 2 + (lane & 1);          // head
    const float dvp = ad1[n * HEADS + hp];
    const int beg = __builtin_amdgcn_readfirstlane(rowptr[n]);
    const int end = __builtin_amdgcn_readfirstlane(rowptr[n + 1]);
    const __half* plane = qh1 + (size_t)hq * QS;
    const int hsel = lane >> 5;                  // consumer head-sub (0/1)
    float acc = 0.f, accw = 0.f;
    // prefetch producer inputs for burst 0 (sentinel-safe)
    int sp = csr[beg + jp];
    float ap = as1[sp * HEADS + hp];
    for (int cs = beg; cs < end; cs += 32) {
        const int m = end - cs;
        const float wo = (jp < m) ? __expf(lrelu(ap + dvp)) : 0.f;
        if (cs + 32 < end) {                     // prefetch next burst's producer inputs
            sp = csr[cs + 32 + jp];
            ap = as1[sp * HEADS + hp];
        }
        const int mm = (m < 32) ? m : 32;
        int jj = 0;
        for (; jj + 8 <= mm; jj += 8) {
            int s[8]; float g[8], w[8];
#pragma unroll
            for (int k = 0; k < 8; k++) s[k] = csr[cs + jj + k];      // scalar loads
#pragma unroll
            for (int k = 0; k < 8; k++) g[k] = __half2float(plane[(size_t)s[k] * 64 + lane]);
#pragma unroll
            for (int k = 0; k < 8; k++) w[k] = __shfl(wo, ((jj + k) << 1) | hsel, 64);
#pragma unroll
            for (int k = 0; k < 8; k++) { accw += w[k]; acc = fmaf(w[k], g[k], acc); }
        }
        for (; jj < mm; jj++) {
            const int s = csr[cs + jj];
            const float g = __half2float(plane[(size_t)s * 64 + lane]);
            const float w = __shfl(wo, (jj << 1) | hsel, 64);
            accw += w; acc = fmaf(w, g, acc);
        }
    }
    float o = acc / accw + b1[ch];
    o = (o > 0.f) ? o : (__expf(o) - 1.f);
    h1p[(size_t)n * C1 + ch] = __float2half(o);
}

// ---- K7: h2 = h1p @ W2 via MFMA (NC=40 padded to 3x16 col tiles); fused as2/ad2.
//      h2h stored with row stride NCP=64 halves (128B = exactly one cache line).
__global__ __launch_bounds__(256) void k_gemm2_mfma(
    const __half* __restrict__ h1p, const _Float16* __restrict__ w2sw,
    const float* __restrict__ a2s, const float* __restrict__ a2d,
    __half* __restrict__ h2h, float* __restrict__ as2, float* __restrict__ ad2)
{
    const int lane = threadIdx.x & 63;
    const int wid = (blockIdx.x * 256 + threadIdx.x) >> 6;
    const int m0 = wid * 16;
    const int g = lane >> 4, lm = lane & 15;
    const int arow = m0 + lm;
    half8 a[8];
    if (arow < N) {
        const __half* hr = h1p + (size_t)arow * C1;
#pragma unroll
        for (int ks = 0; ks < 8; ks++)
            a[ks] = *reinterpret_cast<const half8*>(&hr[ks * 32 + g * 8]);
    } else {
#pragma unroll
        for (int ks = 0; ks < 8; ks++) {
            half8 t;
#pragma unroll
            for (int j = 0; j < 8; j++) t[j] = (_Float16)0.f;
            a[ks] = t;
        }
    }
    f32x4 acc[3];
#pragma unroll
    for (int nt = 0; nt < 3; nt++) acc[nt] = (f32x4){0.f, 0.f, 0.f, 0.f};
#pragma unroll
    for (int ks = 0; ks < 8; ks++) {
#pragma unroll
        for (int nt = 0; nt < 3; nt++) {
            const half8 bfr = *reinterpret_cast<const half8*>(&w2sw[(size_t)((ks * 3 + nt) * 64 + lane) * 8]);
            acc[nt] = __builtin_amdgcn_mfma_f32_16x16x32_f16(a[ks], bfr, acc[nt], 0, 0, 0);
        }
    }
    const int rbase = m0 + g * 4;
    float av[3], dvv[3];
#pragma unroll
    for (int nt = 0; nt < 3; nt++) {
        const int col = nt * 16 + lm;
        av[nt]  = (col < NC) ? a2s[col] : 0.f;
        dvv[nt] = (col < NC) ? a2d[col] : 0.f;
    }
#pragma unroll
    for (int r = 0; r < 4; r++) {
        const int row = rbase + r;
        float ps = 0.f, pd = 0.f;
#pragma unroll
        for (int nt = 0; nt < 3; nt++) {
            const float v = (float)acc[nt][r];
            const int col = nt * 16 + lm;
            if (row < N && col < NC) h2h[(size_t)row * NCP + col] = __float2half(v);
            ps = fmaf(v, av[nt], ps);
            pd = fmaf(v, dvv[nt], pd);
        }
#pragma unroll
        for (int off = 1; off <= 8; off <<= 1) {
            ps += __shfl_xor(ps, off);
            pd += __shfl_xor(pd, off);
        }
        if (lm == 0 && row < N) { as2[row] = ps; ad2[row] = pd; }
    }
}

// ---- K8: layer-2 aggregation + bias + log_softmax. One wave/node, unroll 8.
//      h2h padded to one line/row and fully L2-resident (2.56 MB).
__global__ __launch_bounds__(256) void k_agg2(
    const int* __restrict__ rowptr, const int* __restrict__ csr,
    const __half* __restrict__ h2h, const float* __restrict__ as2,
    const float* __restrict__ ad2, const float* __restrict__ b2,
    float* __restrict__ out)
{
    const int lane = threadIdx.x & 63;
    const int n = (blockIdx.x * blockDim.x + threadIdx.x) >> 6;
    const int c = lane;
    const int cc = (c < NC) ? c : (NC - 1);
    const float adv = ad2[n];
    const int beg = rowptr[n], end = rowptr[n + 1];
    float acc = 0.f, accw = 0.f;
    int e = beg;
    for (; e + 7 < end; e += 8) {
        int s[8];
        float w[8], g[8];
#pragma unroll
        for (int j = 0; j < 8; j++) s[j] = csr[e + j];
#pragma unroll
        for (int j = 0; j < 8; j++) w[j] = __expf(lrelu(as2[s[j]] + adv));
#pragma unroll
        for (int j = 0; j < 8; j++) g[j] = __half2float(h2h[(size_t)s[j] * NCP + cc]);
#pragma unroll
        for (int j = 0; j < 8; j++) {
            accw += w[j];
            acc = fmaf(w[j], g[j], acc);
        }
    }
    for (; e + 3 < end; e += 4) {
        const int s0 = csr[e], s1 = csr[e + 1], s2 = csr[e + 2], s3 = csr[e + 3];
        const float w0 = __expf(lrelu(as2[s0] + adv));
        const float w1 = __expf(lrelu(as2[s1] + adv));
        const float w2 = __expf(lrelu(as2[s2] + adv));
        const float w3 = __expf(lrelu(as2[s3] + adv));
        const float g0 = __half2float(h2h[(size_t)s0 * NCP + cc]);
        const float g1 = __half2float(h2h[(size_t)s1 * NCP + cc]);
        const float g2 = __half2float(h2h[(size_t)s2 * NCP + cc]);
        const float g3 = __half2float(h2h[(size_t)s3 * NCP + cc]);
        accw += (w0 + w1) + (w2 + w3);
        acc = fmaf(w0, g0, acc);
        acc = fmaf(w1, g1, acc);
        acc = fmaf(w2, g2, acc);
        acc = fmaf(w3, g3, acc);
    }
    for (; e < end; e++) {
        const int s = csr[e];
        const float w = __expf(lrelu(as2[s] + adv));
        accw += w;
        acc = fmaf(w, __half2float(h2h[(size_t)s * NCP + cc]), acc);
    }
    const float v = acc / accw + b2[cc];
    float m = (c < NC) ? v : -1e30f;
#pragma unroll
    for (int off = 32; off >= 1; off >>= 1) m = fmaxf(m, __shfl_xor(m, off));
    float S = (c < NC) ? __expf(v - m) : 0.f;
#pragma unroll
    for (int off = 32; off >= 1; off >>= 1) S += __shfl_xor(S, off);
    if (c < NC) out[(size_t)n * NC + c] = v - m - logf(S);
}

extern "C" void kernel_launch(void* const* d_in, const int* in_sizes, int n_in,
                              void* d_out, int out_size, void* d_ws, size_t ws_size,
                              hipStream_t stream)
{
    const float* x   = (const float*)d_in[0];
    const int*   ei  = (const int*)d_in[1];
    const float* W1  = (const float*)d_in[2];
    const float* a1s = (const float*)d_in[3];
    const float* a1d = (const float*)d_in[4];
    const float* b1  = (const float*)d_in[5];
    const float* W2  = (const float*)d_in[6];
    const float* a2s = (const float*)d_in[7];
    const float* a2d = (const float*)d_in[8];
    const float* b2  = (const float*)d_in[9];
    float* out = (float*)d_out;

    const int E  = in_sizes[1] / 2;
    const int ET = E + N;

    auto align64 = [](size_t v) { return (v + 63) & ~(size_t)63; };
    char* ws = (char*)d_ws;
    size_t off = 0;
    _Float16* w1sw = (_Float16*)(ws + off); off = align64(off + (size_t)4096 * 8 * 2);
    _Float16* w2sw = (_Float16*)(ws + off); off = align64(off + (size_t)1536 * 8 * 2);
    __half* qh1 = (__half*)(ws + off); off = align64(off + (size_t)N * C1 * 2);   // 4 quarter planes
    __half* h1p = (__half*)(ws + off); off = align64(off + (size_t)N * C1 * 2);
    __half* h2h = (__half*)(ws + off); off = align64(off + (size_t)N * NCP * 2);
    float* as1 = (float*)(ws + off); off = align64(off + (size_t)N * HEADS * 4);
    float* ad1 = (float*)(ws + off); off = align64(off + (size_t)N * HEADS * 4);
    float* as2 = (float*)(ws + off); off = align64(off + (size_t)N * 4);
    float* ad2 = (float*)(ws + off); off = align64(off + (size_t)N * 4);
    int* hist   = (int*)(ws + off); off = align64(off + (size_t)HM * 4);
    int* buck   = (int*)(ws + off); off = align64(off + (size_t)ET * 4);
    int* rowptr = (int*)(ws + off); off = align64(off + (size_t)(N + 1) * 4);
    int* csr    = (int*)(ws + off); off = align64(off + (size_t)ET * 4 + 128);

    k_misc<<<PREPW_BLOCKS + W2PW_BLOCKS + HBLOCKS, 256, 0, stream>>>(W1, w1sw, W2, w2sw, ei, E, hist);
    k_gemm1_mfma<<<313, 256, 0, stream>>>(x, w1sw, a1s, a1d, qh1, as1, ad1);
    k_hscan2<<<NB, 256, 0, stream>>>(hist);
    k_scatter<<<HBLOCKS, 256, 0, stream>>>(ei, E, hist, buck);
    k_bucket<<<NB, 256, 0, stream>>>(hist, buck, ET, csr, rowptr);
    k_agg1<<<N, 256, 0, stream>>>(rowptr, csr, qh1, as1, ad1, b1, h1p);
    k_gemm2_mfma<<<313, 256, 0, stream>>>(h1p, w2sw, a2s, a2d, h2h, as2, ad2);
    k_agg2<<<5000, 256, 0, stream>>>(rowptr, csr, h2h, as2, ad2, b2, out);
}